// Round 4
// baseline (2777.069 us; speedup 1.0000x reference)
//
#include <hip/hip_runtime.h>
#include <math.h>

// Problem constants (from setup_inputs): B=4, C=64, H=W=128, max_steps=50
#define BATCH 4
#define CCH   64
#define HDIM  128
#define WDIM  128
#define HW    (HDIM * WDIM)          // 16384
#define NELEM (BATCH * CCH * HW)     // 4194304
#define OCH   128                    // 2C
#define NSTEPS 50
#define NBLK  1024
#define DT 0.1f
#define THRESH 0.01f

typedef short bf16x8 __attribute__((ext_vector_type(8)));
typedef float f32x4  __attribute__((ext_vector_type(4)));

struct Ctl {
    int done;
    int steps;
};

__global__ void init_kernel(Ctl* ctl, double* accum, unsigned* cnt) {
    int t = threadIdx.x;
    if (t == 0) { ctl->done = 0; ctl->steps = 0; }
    if (t < NSTEPS) { accum[t] = 0.0; cnt[t] = 0u; }
}

__device__ __forceinline__ short f2bf(float x) {
    unsigned u = __float_as_uint(x);
    unsigned r = u + 0x7fff + ((u >> 16) & 1);   // RNE
    return (short)(r >> 16);
}

__device__ __forceinline__ int pk(float a, float b) {
    return (f2bf(a) & 0xffff) | (((int)f2bf(b)) << 16);
}

// Convert w1 [128][64] and w2 [64][128] to bf16 (natural layouts; both serve
// as MFMA A-operands directly: lane&15 indexes the M dim, k contiguous).
__global__ void prep_kernel(const float* __restrict__ w1,
                            const float* __restrict__ w2,
                            short* __restrict__ w1b, short* __restrict__ w2b) {
    int i = blockIdx.x * blockDim.x + threadIdx.x;
    if (i < OCH * CCH) {
        w1b[i] = f2bf(w1[i]);
        w2b[i] = f2bf(w2[i]);
    }
}

// Branchless exact-enough GeLU: erf via Abramowitz-Stegun 7.1.26
// (|err_erf| <= 1.5e-7 -> gelu error << bf16 rounding that h receives anyway)
__device__ __forceinline__ float gelu_fast(float x) {
    float u  = x * 0.70710678118654752f;
    float au = fabsf(u);
    float t  = __builtin_amdgcn_rcpf(fmaf(0.3275911f, au, 1.0f));
    float p  = fmaf(1.061405429f, t, -1.453152027f);
    p = fmaf(p, t, 1.421413741f);
    p = fmaf(p, t, -0.284496736f);
    p = fmaf(p, t, 0.254829592f);
    p = p * t;
    float ex = __expf(-au * au);
    float e  = fmaf(-p, ex, 1.0f);        // erf(|u|)
    float er = copysignf(e, x);           // erf(u)
    return 0.5f * x * (1.0f + er);
}

// Block = 256 threads = 4 waves, 64 consecutive pixels of one row.
// XCD swizzle: blk%8 = XCD (round-robin dispatch) -> XCD x owns rows
// [16x,16x+16) so the field slice + conv taps stay in that XCD's L2.
// GEMM1: h[128][64px] = gelu(w1 x f + b1)  via 16x16x32 bf16 MFMA
// GEMM2: react[64][64px] = w2 x h + b2     via 16x16x32 bf16 MFMA
// Conv 3x3 + Euler update fp32 on VALU. Finalize fused (last-block-out).
__global__ __launch_bounds__(256, 4) void step_kernel(
    const float* __restrict__ fin, float* __restrict__ fout,
    const float* __restrict__ dw, const float* __restrict__ db,
    const short* __restrict__ w1b, const float* __restrict__ b1,
    const short* __restrict__ w2b, const float* __restrict__ b2,
    const float* __restrict__ dcoeff, Ctl* __restrict__ ctl,
    double* __restrict__ accum, unsigned* __restrict__ cnt, int sidx)
{
    if (ctl->done) return;   // field frozen after convergence

    const int tid  = threadIdx.x;
    const int lane = tid & 63;
    const int w    = tid >> 6;        // wave id
    const int quad = (lane >> 4);     // 0..3
    const int lp   = lane & 15;
    const int blk  = blockIdx.x;
    // XCD-aware decode: y-slab per XCD
    const int xcd  = blk & 7;
    const int idx  = blk >> 3;
    const int y    = xcd * 16 + (idx & 15);
    const int b    = (idx >> 4) & 3;
    const int seg  = idx >> 6;
    const int px0  = seg * 64;

    // LDS: f tile bf16 [px][ch] (granule-XOR-swizzled), h tile bf16 [px][o]
    __shared__ int4  sBf4[64 * 8];    // 8 KB : 64 px x 64 ch bf16
    __shared__ int4  sH4 [64 * 16];   // 16 KB: 64 px x 128 o bf16
    __shared__ float sDw[CCH * 9];    // 2.25 KB
    __shared__ float sDb[CCH];
    __shared__ float wred[4];
    short* sBf = (short*)sBf4;
    short* sH  = (short*)sH4;

    // Stage conv weights into LDS
    for (int i = tid; i < CCH * 9; i += 256) sDw[i] = dw[i];
    if (tid < CCH) sDb[tid] = db[tid];

    // A-fragments for GEMM1 (w1 bf16 [o][c]): o = w*32+mt*16+lp, k = kk*32+quad*8+j
    bf16x8 a1[2][2];
    #pragma unroll
    for (int mt = 0; mt < 2; ++mt)
        #pragma unroll
        for (int kk = 0; kk < 2; ++kk)
            a1[mt][kk] = *(const bf16x8*)(w1b + (w * 32 + mt * 16 + lp) * CCH
                                          + kk * 32 + quad * 8);
    // Per-lane biases
    f32x4 b1v[2];
    #pragma unroll
    for (int mt = 0; mt < 2; ++mt)
        b1v[mt] = *(const f32x4*)(b1 + w * 32 + mt * 16 + quad * 4);
    f32x4 b2v = *(const f32x4*)(b2 + w * 16 + quad * 4);

    // Phase A: load own channel quarter (px = lane), convert, swizzled LDS store
    {
        const int base = b * CCH * HW + y * WDIM + px0 + lane;
        float f[16];
        #pragma unroll
        for (int i = 0; i < 16; ++i)
            f[i] = fin[base + (w * 16 + i) * HW];
        int4 v0, v1;
        v0.x = pk(f[0], f[1]);  v0.y = pk(f[2], f[3]);
        v0.z = pk(f[4], f[5]);  v0.w = pk(f[6], f[7]);
        v1.x = pk(f[8], f[9]);  v1.y = pk(f[10], f[11]);
        v1.z = pk(f[12], f[13]); v1.w = pk(f[14], f[15]);
        int g0 = (w * 2)     ^ (lane & 7);
        int g1 = (w * 2 + 1) ^ (lane & 7);
        sBf4[lane * 8 + g0] = v0;
        sBf4[lane * 8 + g1] = v1;
    }
    __syncthreads();

    // GEMM1: acc1[mt][nt] = w1 tile x f tile   (K = 64, 16 MFMA / wave)
    f32x4 acc1[2][4];
    #pragma unroll
    for (int mt = 0; mt < 2; ++mt)
        #pragma unroll
        for (int nt = 0; nt < 4; ++nt)
            acc1[mt][nt] = (f32x4)0.0f;

    #pragma unroll
    for (int kk = 0; kk < 2; ++kk) {
        #pragma unroll
        for (int nt = 0; nt < 4; ++nt) {
            int px = nt * 16 + lp;
            int g  = kk * 4 + quad;
            bf16x8 bfrag = *(const bf16x8*)(sBf + px * 64 + (g ^ (px & 7)) * 8);
            #pragma unroll
            for (int mt = 0; mt < 2; ++mt)
                acc1[mt][nt] = __builtin_amdgcn_mfma_f32_16x16x32_bf16(
                    a1[mt][kk], bfrag, acc1[mt][nt], 0, 0, 0);
        }
    }

    // Bias + GeLU, write h to LDS (bf16, granule-swizzled [px][o])
    #pragma unroll
    for (int mt = 0; mt < 2; ++mt) {
        #pragma unroll
        for (int nt = 0; nt < 4; ++nt) {
            int px = nt * 16 + lp;
            float h0 = gelu_fast(acc1[mt][nt][0] + b1v[mt][0]);
            float h1 = gelu_fast(acc1[mt][nt][1] + b1v[mt][1]);
            float h2 = gelu_fast(acc1[mt][nt][2] + b1v[mt][2]);
            float h3 = gelu_fast(acc1[mt][nt][3] + b1v[mt][3]);
            int o0  = w * 32 + mt * 16 + quad * 4;
            int g   = o0 >> 3;
            int sub = o0 & 7;           // 0 or 4
            int gp  = (g & 8) | ((g ^ (px & 7)) & 7);
            int2 hv; hv.x = pk(h0, h1); hv.y = pk(h2, h3);
            *(int2*)(sH + px * 128 + gp * 8 + sub) = hv;
        }
    }
    __syncthreads();

    // GEMM2: acc2[nt] = w2 tile x h tile   (K = 128, 16 MFMA / wave)
    bf16x8 a2[4];
    #pragma unroll
    for (int kk = 0; kk < 4; ++kk)
        a2[kk] = *(const bf16x8*)(w2b + (w * 16 + lp) * OCH + kk * 32 + quad * 8);

    f32x4 acc2[4];
    #pragma unroll
    for (int nt = 0; nt < 4; ++nt) acc2[nt] = (f32x4)0.0f;

    #pragma unroll
    for (int kk = 0; kk < 4; ++kk) {
        #pragma unroll
        for (int nt = 0; nt < 4; ++nt) {
            int px = nt * 16 + lp;
            int g  = kk * 4 + quad;
            int gp = (g & 8) | ((g ^ (px & 7)) & 7);
            bf16x8 hfrag = *(const bf16x8*)(sH + px * 128 + gp * 8);
            acc2[nt] = __builtin_amdgcn_mfma_f32_16x16x32_bf16(
                a2[kk], hfrag, acc2[nt], 0, 0, 0);
        }
    }

    // Phase C: depthwise 3x3 (fp32) + Euler update + change sum.
    // Thread owns c = w*16 + quad*4 + r (r=0..3), px = nt*16 + lp (nt=0..3).
    const float dc = dcoeff[0];
    const bool ym = (y > 0), yp = (y < HDIM - 1);
    float csum = 0.0f;

    #pragma unroll
    for (int r = 0; r < 4; ++r) {
        const int c = w * 16 + quad * 4 + r;
        const float* wk = sDw + c * 9;    // LDS broadcast within quad
        float k0 = wk[0], k1 = wk[1], k2 = wk[2];
        float k3 = wk[3], k4 = wk[4], k5 = wk[5];
        float k6 = wk[6], k7 = wk[7], k8 = wk[8];
        float dbc = sDb[c];
        #pragma unroll
        for (int nt = 0; nt < 4; ++nt) {
            const int px = nt * 16 + lp;
            const int x  = px0 + px;
            const bool xm = (x > 0), xp = (x < WDIM - 1);
            const float* rc = fin + b * CCH * HW + c * HW + y * WDIM + x;

            float a0 = (ym && xm) ? rc[-WDIM - 1] : 0.0f;
            float a1v = ym        ? rc[-WDIM]     : 0.0f;
            float a2v = (ym && xp) ? rc[-WDIM + 1] : 0.0f;
            float m0 = xm ? rc[-1] : 0.0f;
            float m1 = rc[0];
            float m2 = xp ? rc[1]  : 0.0f;
            float p0 = (yp && xm) ? rc[WDIM - 1] : 0.0f;
            float p1 = yp         ? rc[WDIM]     : 0.0f;
            float p2 = (yp && xp) ? rc[WDIM + 1] : 0.0f;

            float d = dbc;
            d += k0 * a0 + k1 * a1v + k2 * a2v;
            d += k3 * m0 + k4 * m1  + k5 * m2;
            d += k6 * p0 + k7 * p1  + k8 * p2;

            float react = acc2[nt][r] + b2v[r];
            float nf = m1 + DT * (dc * d + react);
            fout[b * CCH * HW + c * HW + y * WDIM + x] = nf;
            csum += fabsf(nf - m1);
        }
    }

    // Reduce csum: wave shuffle -> LDS -> one fp64 atomic per block,
    // then fused finalize: last block out updates ctl for the next step.
    float v = csum;
    #pragma unroll
    for (int off = 32; off > 0; off >>= 1) v += __shfl_down(v, off, 64);
    if (lane == 0) wred[w] = v;
    __syncthreads();
    if (tid == 0) {
        double s = (double)wred[0] + (double)wred[1]
                 + (double)wred[2] + (double)wred[3];
        atomicAdd(&accum[sidx], s);
        __threadfence();
        unsigned old = atomicAdd(&cnt[sidx], 1u);
        if (old == NBLK - 1) {
            __threadfence();
            double a = __hip_atomic_load(&accum[sidx], __ATOMIC_RELAXED,
                                         __HIP_MEMORY_SCOPE_AGENT);
            ctl->steps = ctl->steps + 1;
            float change = (float)(a * (1.0 / (double)NELEM));
            if (change < THRESH) ctl->done = 1;
        }
    }
}

// Resolve ping-pong parity: final field is in bufA if steps is odd; steps -> float
__global__ void output_kernel(const float* __restrict__ bufA,
                              float* __restrict__ out,
                              const Ctl* __restrict__ ctl)
{
    int i = blockIdx.x * blockDim.x + threadIdx.x;
    bool fromA = (((ctl->steps - 1) & 1) == 0);
    if (i < NELEM && fromA) out[i] = bufA[i];
    if (i == 0) out[NELEM] = (float)ctl->steps;
}

extern "C" void kernel_launch(void* const* d_in, const int* in_sizes, int n_in,
                              void* d_out, int out_size, void* d_ws, size_t ws_size,
                              hipStream_t stream)
{
    const float* field  = (const float*)d_in[0];
    const float* dw     = (const float*)d_in[1];
    const float* db     = (const float*)d_in[2];
    const float* w1     = (const float*)d_in[3];
    const float* b1     = (const float*)d_in[4];
    const float* w2     = (const float*)d_in[5];
    const float* b2     = (const float*)d_in[6];
    const float* dcoeff = (const float*)d_in[7];
    // d_in[8] = max_steps (50, fixed by setup_inputs)

    float* out = (float*)d_out;

    char* ws = (char*)d_ws;
    float*    bufA  = (float*)ws;                                     // 16 MiB
    Ctl*      ctl   = (Ctl*)(ws + (size_t)NELEM * 4);                 // 8 B
    short*    w1b   = (short*)(ws + (size_t)NELEM * 4 + 256);         // 16 KB
    short*    w2b   = (short*)(ws + (size_t)NELEM * 4 + 256 + 16384); // 16 KB
    double*   accum = (double*)(ws + (size_t)NELEM * 4 + 256 + 32768);// 400 B
    unsigned* cnt   = (unsigned*)(ws + (size_t)NELEM * 4 + 256 + 32768 + 512);

    init_kernel<<<1, 64, 0, stream>>>(ctl, accum, cnt);
    prep_kernel<<<(OCH * CCH + 255) / 256, 256, 0, stream>>>(w1, w2, w1b, w2b);

    float* bufs[2] = { bufA, out };   // step s (1-indexed) writes bufs[(s-1)&1]
    const float* fin = field;
    for (int s = 1; s <= NSTEPS; ++s) {
        float* fout = bufs[(s - 1) & 1];
        step_kernel<<<NBLK, 256, 0, stream>>>(
            fin, fout, dw, db, w1b, b1, w2b, b2, dcoeff, ctl, accum, cnt, s - 1);
        fin = fout;
    }

    output_kernel<<<(NELEM + 255) / 256, 256, 0, stream>>>(bufA, out, ctl);
}

// Round 5
// 1177.740 us; speedup vs baseline: 2.3580x; 2.3580x over previous
//
#include <hip/hip_runtime.h>
#include <math.h>

// Problem constants (from setup_inputs): B=4, C=64, H=W=128, max_steps=50
#define BATCH 4
#define CCH   64
#define HDIM  128
#define WDIM  128
#define HW    (HDIM * WDIM)          // 16384
#define NELEM (BATCH * CCH * HW)     // 4194304
#define OCH   128                    // 2C
#define NSTEPS 50
#define NBLK  1024
#define DT 0.1f
#define THRESH 0.01f

typedef short bf16x8 __attribute__((ext_vector_type(8)));
typedef float f32x4  __attribute__((ext_vector_type(4)));

struct Ctl {
    int done;
    int steps;
};

__global__ void init_kernel(Ctl* ctl) {
    ctl->done = 0;
    ctl->steps = 0;
}

__device__ __forceinline__ short f2bf(float x) {
    unsigned u = __float_as_uint(x);
    unsigned r = u + 0x7fff + ((u >> 16) & 1);   // RNE
    return (short)(r >> 16);
}

__device__ __forceinline__ int pk(float a, float b) {
    return (f2bf(a) & 0xffff) | (((int)f2bf(b)) << 16);
}

// Convert w1 [128][64] and w2 [64][128] to bf16 (natural layouts; both serve
// as MFMA A-operands directly: lane&15 indexes the M dim, k contiguous).
__global__ void prep_kernel(const float* __restrict__ w1,
                            const float* __restrict__ w2,
                            short* __restrict__ w1b, short* __restrict__ w2b) {
    int i = blockIdx.x * blockDim.x + threadIdx.x;
    if (i < OCH * CCH) {
        w1b[i] = f2bf(w1[i]);
        w2b[i] = f2bf(w2[i]);
    }
}

// Branchless GeLU: erf via Abramowitz-Stegun 7.1.26
// (|err_erf| <= 1.5e-7 -> gelu error << bf16 rounding that h receives anyway)
__device__ __forceinline__ float gelu_fast(float x) {
    float u  = x * 0.70710678118654752f;
    float au = fabsf(u);
    float t  = __builtin_amdgcn_rcpf(fmaf(0.3275911f, au, 1.0f));
    float p  = fmaf(1.061405429f, t, -1.453152027f);
    p = fmaf(p, t, 1.421413741f);
    p = fmaf(p, t, -0.284496736f);
    p = fmaf(p, t, 0.254829592f);
    p = p * t;
    float ex = __expf(-au * au);
    float e  = fmaf(-p, ex, 1.0f);        // erf(|u|)
    float er = copysignf(e, x);           // erf(u)
    return 0.5f * x * (1.0f + er);
}

// Block = 256 threads = 4 waves, 64 consecutive pixels of one row.
// XCD swizzle: blk%8 = XCD (round-robin dispatch, verified by FETCH_SIZE
// 45.7->9.3 MB/step in R4) -> XCD x owns rows [16x,16x+16): the ping-pong
// slab stays in that XCD's L2 across steps.
// GEMM1: h[128][64px] = gelu(w1 x f + b1)  via 16x16x32 bf16 MFMA
// GEMM2: react[64][64px] = w2 x h + b2     via 16x16x32 bf16 MFMA
// Conv 3x3 + Euler update fp32 on VALU.
// NO fences / NO contended atomics: per-block partial -> psum[blk] plain
// store; the separate finalize kernel gets visibility from the kernel
// boundary. (R4's __threadfence = buffer_wbl2 per block was the regression.)
__global__ __launch_bounds__(256, 4) void step_kernel(
    const float* __restrict__ fin, float* __restrict__ fout,
    const float* __restrict__ dw, const float* __restrict__ db,
    const short* __restrict__ w1b, const float* __restrict__ b1,
    const short* __restrict__ w2b, const float* __restrict__ b2,
    const float* __restrict__ dcoeff, const Ctl* __restrict__ ctl,
    double* __restrict__ psum)
{
    if (ctl->done) return;   // field frozen after convergence

    const int tid  = threadIdx.x;
    const int lane = tid & 63;
    const int w    = tid >> 6;        // wave id
    const int quad = (lane >> 4);     // 0..3
    const int lp   = lane & 15;
    const int blk  = blockIdx.x;
    // XCD-aware decode: y-slab per XCD
    const int xcd  = blk & 7;
    const int idx  = blk >> 3;
    const int y    = xcd * 16 + (idx & 15);
    const int b    = (idx >> 4) & 3;
    const int seg  = idx >> 6;
    const int px0  = seg * 64;

    // LDS: f tile bf16 [px][ch] (granule-XOR-swizzled), h tile bf16 [px][o]
    __shared__ int4  sBf4[64 * 8];    // 8 KB : 64 px x 64 ch bf16
    __shared__ int4  sH4 [64 * 16];   // 16 KB: 64 px x 128 o bf16
    __shared__ float sDw[CCH * 9];    // 2.25 KB
    __shared__ float sDb[CCH];
    __shared__ float wred[4];
    short* sBf = (short*)sBf4;
    short* sH  = (short*)sH4;

    // Stage conv weights into LDS
    for (int i = tid; i < CCH * 9; i += 256) sDw[i] = dw[i];
    if (tid < CCH) sDb[tid] = db[tid];

    // A-fragments for GEMM1 (w1 bf16 [o][c]): o = w*32+mt*16+lp, k = kk*32+quad*8+j
    bf16x8 a1[2][2];
    #pragma unroll
    for (int mt = 0; mt < 2; ++mt)
        #pragma unroll
        for (int kk = 0; kk < 2; ++kk)
            a1[mt][kk] = *(const bf16x8*)(w1b + (w * 32 + mt * 16 + lp) * CCH
                                          + kk * 32 + quad * 8);
    // Per-lane biases
    f32x4 b1v[2];
    #pragma unroll
    for (int mt = 0; mt < 2; ++mt)
        b1v[mt] = *(const f32x4*)(b1 + w * 32 + mt * 16 + quad * 4);
    f32x4 b2v = *(const f32x4*)(b2 + w * 16 + quad * 4);

    // Phase A: load own channel quarter (px = lane), convert, swizzled LDS store
    {
        const int base = b * CCH * HW + y * WDIM + px0 + lane;
        float f[16];
        #pragma unroll
        for (int i = 0; i < 16; ++i)
            f[i] = fin[base + (w * 16 + i) * HW];
        int4 v0, v1;
        v0.x = pk(f[0], f[1]);  v0.y = pk(f[2], f[3]);
        v0.z = pk(f[4], f[5]);  v0.w = pk(f[6], f[7]);
        v1.x = pk(f[8], f[9]);  v1.y = pk(f[10], f[11]);
        v1.z = pk(f[12], f[13]); v1.w = pk(f[14], f[15]);
        int g0 = (w * 2)     ^ (lane & 7);
        int g1 = (w * 2 + 1) ^ (lane & 7);
        sBf4[lane * 8 + g0] = v0;
        sBf4[lane * 8 + g1] = v1;
    }
    __syncthreads();

    // GEMM1: acc1[mt][nt] = w1 tile x f tile   (K = 64, 16 MFMA / wave)
    f32x4 acc1[2][4];
    #pragma unroll
    for (int mt = 0; mt < 2; ++mt)
        #pragma unroll
        for (int nt = 0; nt < 4; ++nt)
            acc1[mt][nt] = (f32x4)0.0f;

    #pragma unroll
    for (int kk = 0; kk < 2; ++kk) {
        #pragma unroll
        for (int nt = 0; nt < 4; ++nt) {
            int px = nt * 16 + lp;
            int g  = kk * 4 + quad;
            bf16x8 bfrag = *(const bf16x8*)(sBf + px * 64 + (g ^ (px & 7)) * 8);
            #pragma unroll
            for (int mt = 0; mt < 2; ++mt)
                acc1[mt][nt] = __builtin_amdgcn_mfma_f32_16x16x32_bf16(
                    a1[mt][kk], bfrag, acc1[mt][nt], 0, 0, 0);
        }
    }

    // Bias + GeLU, write h to LDS (bf16, granule-swizzled [px][o])
    #pragma unroll
    for (int mt = 0; mt < 2; ++mt) {
        #pragma unroll
        for (int nt = 0; nt < 4; ++nt) {
            int px = nt * 16 + lp;
            float h0 = gelu_fast(acc1[mt][nt][0] + b1v[mt][0]);
            float h1 = gelu_fast(acc1[mt][nt][1] + b1v[mt][1]);
            float h2 = gelu_fast(acc1[mt][nt][2] + b1v[mt][2]);
            float h3 = gelu_fast(acc1[mt][nt][3] + b1v[mt][3]);
            int o0  = w * 32 + mt * 16 + quad * 4;
            int g   = o0 >> 3;
            int sub = o0 & 7;           // 0 or 4
            int gp  = (g & 8) | ((g ^ (px & 7)) & 7);
            int2 hv; hv.x = pk(h0, h1); hv.y = pk(h2, h3);
            *(int2*)(sH + px * 128 + gp * 8 + sub) = hv;
        }
    }
    __syncthreads();

    // GEMM2: acc2[nt] = w2 tile x h tile   (K = 128, 16 MFMA / wave)
    bf16x8 a2[4];
    #pragma unroll
    for (int kk = 0; kk < 4; ++kk)
        a2[kk] = *(const bf16x8*)(w2b + (w * 16 + lp) * OCH + kk * 32 + quad * 8);

    f32x4 acc2[4];
    #pragma unroll
    for (int nt = 0; nt < 4; ++nt) acc2[nt] = (f32x4)0.0f;

    #pragma unroll
    for (int kk = 0; kk < 4; ++kk) {
        #pragma unroll
        for (int nt = 0; nt < 4; ++nt) {
            int px = nt * 16 + lp;
            int g  = kk * 4 + quad;
            int gp = (g & 8) | ((g ^ (px & 7)) & 7);
            bf16x8 hfrag = *(const bf16x8*)(sH + px * 128 + gp * 8);
            acc2[nt] = __builtin_amdgcn_mfma_f32_16x16x32_bf16(
                a2[kk], hfrag, acc2[nt], 0, 0, 0);
        }
    }

    // Phase C: depthwise 3x3 (fp32) + Euler update + change sum.
    // Thread owns c = w*16 + quad*4 + r (r=0..3), px = nt*16 + lp (nt=0..3).
    const float dc = dcoeff[0];
    const bool ym = (y > 0), yp = (y < HDIM - 1);
    float csum = 0.0f;

    #pragma unroll
    for (int r = 0; r < 4; ++r) {
        const int c = w * 16 + quad * 4 + r;
        const float* wk = sDw + c * 9;    // LDS broadcast within quad
        float k0 = wk[0], k1 = wk[1], k2 = wk[2];
        float k3 = wk[3], k4 = wk[4], k5 = wk[5];
        float k6 = wk[6], k7 = wk[7], k8 = wk[8];
        float dbc = sDb[c];
        #pragma unroll
        for (int nt = 0; nt < 4; ++nt) {
            const int px = nt * 16 + lp;
            const int x  = px0 + px;
            const bool xm = (x > 0), xp = (x < WDIM - 1);
            const float* rc = fin + b * CCH * HW + c * HW + y * WDIM + x;

            float a0 = (ym && xm) ? rc[-WDIM - 1] : 0.0f;
            float a1v = ym        ? rc[-WDIM]     : 0.0f;
            float a2v = (ym && xp) ? rc[-WDIM + 1] : 0.0f;
            float m0 = xm ? rc[-1] : 0.0f;
            float m1 = rc[0];
            float m2 = xp ? rc[1]  : 0.0f;
            float p0 = (yp && xm) ? rc[WDIM - 1] : 0.0f;
            float p1 = yp         ? rc[WDIM]     : 0.0f;
            float p2 = (yp && xp) ? rc[WDIM + 1] : 0.0f;

            float d = dbc;
            d += k0 * a0 + k1 * a1v + k2 * a2v;
            d += k3 * m0 + k4 * m1  + k5 * m2;
            d += k6 * p0 + k7 * p1  + k8 * p2;

            float react = acc2[nt][r] + b2v[r];
            float nf = m1 + DT * (dc * d + react);
            fout[b * CCH * HW + c * HW + y * WDIM + x] = nf;
            csum += fabsf(nf - m1);
        }
    }

    // Reduce csum: wave shuffle -> LDS -> ONE plain store per block (no
    // atomics, no fences; finalize kernel reads after the kernel boundary).
    float v = csum;
    #pragma unroll
    for (int off = 32; off > 0; off >>= 1) v += __shfl_down(v, off, 64);
    if (lane == 0) wred[w] = v;
    __syncthreads();
    if (tid == 0) {
        psum[blk] = (double)wred[0] + (double)wred[1]
                  + (double)wred[2] + (double)wred[3];
    }
}

__global__ __launch_bounds__(256) void finalize_kernel(
    Ctl* __restrict__ ctl, const double* __restrict__ psum)
{
    if (ctl->done) return;
    __shared__ double sd[256];
    int t = threadIdx.x;
    sd[t] = psum[t] + psum[t + 256] + psum[t + 512] + psum[t + 768];
    __syncthreads();
    for (int off = 128; off > 0; off >>= 1) {
        if (t < off) sd[t] += sd[t + off];
        __syncthreads();
    }
    if (t == 0) {
        ctl->steps += 1;
        float change = (float)(sd[0] * (1.0 / (double)NELEM));
        if (change < THRESH) ctl->done = 1;
    }
}

// Resolve ping-pong parity: final field is in bufA if steps is odd; steps -> float
__global__ void output_kernel(const float* __restrict__ bufA,
                              float* __restrict__ out,
                              const Ctl* __restrict__ ctl)
{
    int i = blockIdx.x * blockDim.x + threadIdx.x;
    bool fromA = (((ctl->steps - 1) & 1) == 0);
    if (i < NELEM && fromA) out[i] = bufA[i];
    if (i == 0) out[NELEM] = (float)ctl->steps;
}

extern "C" void kernel_launch(void* const* d_in, const int* in_sizes, int n_in,
                              void* d_out, int out_size, void* d_ws, size_t ws_size,
                              hipStream_t stream)
{
    const float* field  = (const float*)d_in[0];
    const float* dw     = (const float*)d_in[1];
    const float* db     = (const float*)d_in[2];
    const float* w1     = (const float*)d_in[3];
    const float* b1     = (const float*)d_in[4];
    const float* w2     = (const float*)d_in[5];
    const float* b2     = (const float*)d_in[6];
    const float* dcoeff = (const float*)d_in[7];
    // d_in[8] = max_steps (50, fixed by setup_inputs)

    float* out = (float*)d_out;

    char* ws = (char*)d_ws;
    float*  bufA = (float*)ws;                                     // 16 MiB
    Ctl*    ctl  = (Ctl*)(ws + (size_t)NELEM * 4);                 // 8 B
    short*  w1b  = (short*)(ws + (size_t)NELEM * 4 + 256);         // 16 KB
    short*  w2b  = (short*)(ws + (size_t)NELEM * 4 + 256 + 16384); // 16 KB
    double* psum = (double*)(ws + (size_t)NELEM * 4 + 256 + 32768);// 8 KB

    init_kernel<<<1, 1, 0, stream>>>(ctl);
    prep_kernel<<<(OCH * CCH + 255) / 256, 256, 0, stream>>>(w1, w2, w1b, w2b);

    float* bufs[2] = { bufA, out };   // step s (1-indexed) writes bufs[(s-1)&1]
    const float* fin = field;
    for (int s = 1; s <= NSTEPS; ++s) {
        float* fout = bufs[(s - 1) & 1];
        step_kernel<<<NBLK, 256, 0, stream>>>(
            fin, fout, dw, db, w1b, b1, w2b, b2, dcoeff, ctl, psum);
        finalize_kernel<<<1, 256, 0, stream>>>(ctl, psum);
        fin = fout;
    }

    output_kernel<<<(NELEM + 255) / 256, 256, 0, stream>>>(bufA, out, ctl);
}